// Round 10
// baseline (91.218 us; speedup 1.0000x reference)
//
#include <hip/hip_runtime.h>
#include <math.h>

// Problem constants (B=2, T=4096, n=4, D=2048)
#define DM      8192      // n*D flattened feature dim
#define NK      24        // 4 pre + 4 post + 16 res dot products
#define NACC    25        // + 1 for sum(x^2)
#define NTOK    8192      // B*T tokens
#define NGRP    32        // d-groups across blocks
#define DPG     256       // d per group (weights LDS-resident: 24 KB)
#define TPB     256
#define TOKB    128       // tokens per block (2 th * 16 ts * 4 u)
#define UT      4         // tokens per thread
#define NCH     16        // chunks of 16 d; thread covers 4 d/chunk
#define KHN     12        // coefficients per kh half
#define PPT     28        // padded partials per token (25 used, float4-aligned)

// ---------------------------------------------------------------------------
// Kernel 1: Wc2[grp][k][dloc] = alpha_k * W_k[grp*256+dloc] * rms_w[...]
// k-major per group so partial_k can stage one linear 24 KB block.
// ---------------------------------------------------------------------------
__global__ void combine_w(const float* __restrict__ rms_w,
                          const float* __restrict__ w_pre,
                          const float* __restrict__ w_post,
                          const float* __restrict__ w_res,
                          const float* __restrict__ a_pre,
                          const float* __restrict__ a_post,
                          const float* __restrict__ a_res,
                          float* __restrict__ Wc2) {
    int idx = blockIdx.x * blockDim.x + threadIdx.x;
    if (idx >= NGRP * NK * DPG) return;
    const int grp  = idx / (NK * DPG);
    const int r    = idx - grp * (NK * DPG);
    const int k    = r / DPG;
    const int dloc = r - k * DPG;
    const int d    = grp * DPG + dloc;
    float w, a;
    if (k < 4)      { w = w_pre [(size_t)k       * DM + d]; a = a_pre[0];  }
    else if (k < 8) { w = w_post[(size_t)(k - 4) * DM + d]; a = a_post[0]; }
    else            { w = w_res [(size_t)(k - 8) * DM + d]; a = a_res[0];  }
    Wc2[idx] = a * w * rms_w[d];
}

// async global->LDS, 16B per lane (dest linear: wave-uniform base + lane*16)
__device__ __forceinline__ void load_lds16(const float* g, float* l) {
    __builtin_amdgcn_global_load_lds(
        (const __attribute__((address_space(1))) void*)g,
        (__attribute__((address_space(3))) void*)l, 16, 0, 0);
}

// ---------------------------------------------------------------------------
// Kernel 2: streaming partials. Block = 128 tokens x 256 d.
//  WAVE-LEVEL kh split (R10): wave w of 4: kh = w&1, th = w>>1.
//  Lane = 16 ts x 4 dl -> each x-load wave-instr covers 16 token-rows x 64 B
//  = 1024 UNIQUE bytes (was 512: lane-level kh duplicated addresses in-wave).
//  kh-twin wave reads same addresses -> same-CU L1/L2 hit, no extra HBM.
//  Inner loop body, acc[4][13], xc/xn prefetch, (256,4) all byte-identical
//  to the proven 91us build.
//  R5/R7 lessons: (256,5) capped 48 VGPR -> spill (619us); ping-pong macro
//  restructure -> 64 VGPR spill (709us). Do NOT touch the loop body.
// part layout (token-major, padded): part[(grp*NTOK + token)*28 + c]
// ---------------------------------------------------------------------------
__global__ __launch_bounds__(TPB, 4) void partial_k(const float* __restrict__ x,
                                                    const float* __restrict__ Wc2,
                                                    float* __restrict__ part) {
    __shared__ __align__(16) float wlds[NK * DPG];   // [24][256] k-major, 24 KB

    const int t    = threadIdx.x;
    const int grp  = blockIdx.x;          // 0..31  (fastest -> contiguous rows)
    const int tile = blockIdx.y;          // 0..63

    // ---- stage weights once: 24 KB linear ----
    const float* wsrc = Wc2 + (size_t)grp * (NK * DPG);
#pragma unroll
    for (int ld = 0; ld < 6; ++ld) {
        const int e = (t + ld * TPB) * 4;
        load_lds16(wsrc + e, &wlds[e]);
    }

    const int wave = t >> 6;               // 0..3
    const int lane = t & 63;
    const int kh   = wave & 1;             // coefficient half (wave-uniform)
    const int th   = wave >> 1;            // token half (wave-uniform)
    const int ts   = lane >> 2;            // token slot 0..15
    const int dl   = lane & 3;             // d sublane 0..3
    const int tok0 = tile * TOKB + th * 16 + ts;   // + 32*u
    const float* xp = x + (size_t)tok0 * DM + grp * DPG + dl * 4;

    float acc[UT][13];
#pragma unroll
    for (int u = 0; u < UT; ++u)
#pragma unroll
        for (int kk = 0; kk < 13; ++kk) acc[u][kk] = 0.0f;

    __syncthreads();                      // weights staged (drains vmcnt)

    float xc[UT][4], xn[UT][4];
#pragma unroll
    for (int u = 0; u < UT; ++u) {
        const float4 v = *(const float4*)(xp + (size_t)u * 32 * DM);
        xc[u][0] = v.x; xc[u][1] = v.y; xc[u][2] = v.z; xc[u][3] = v.w;
    }

    for (int c = 0; c < NCH; ++c) {
        if (c + 1 < NCH) {                // uniform branch: prefetch next chunk
#pragma unroll
            for (int u = 0; u < UT; ++u) {
                const float4 v = *(const float4*)(xp + (size_t)u * 32 * DM +
                                                  (c + 1) * 16);
                xn[u][0] = v.x; xn[u][1] = v.y; xn[u][2] = v.z; xn[u][3] = v.w;
            }
        }
        const float* wl = &wlds[kh * (KHN * DPG) + c * 16 + dl * 4];
#pragma unroll
        for (int kk = 0; kk < KHN; ++kk) {
            const float4 w4 = *(const float4*)(wl + kk * DPG);
#pragma unroll
            for (int u = 0; u < UT; ++u) {
                acc[u][kk] = fmaf(xc[u][0], w4.x, acc[u][kk]);
                acc[u][kk] = fmaf(xc[u][1], w4.y, acc[u][kk]);
                acc[u][kk] = fmaf(xc[u][2], w4.z, acc[u][kk]);
                acc[u][kk] = fmaf(xc[u][3], w4.w, acc[u][kk]);
            }
        }
#pragma unroll
        for (int u = 0; u < UT; ++u)      // ss on both kh halves (uniform)
#pragma unroll
            for (int e = 0; e < 4; ++e)
                acc[u][12] = fmaf(xc[u][e], xc[u][e], acc[u][12]);
        if (c + 1 < NCH) {
#pragma unroll
            for (int u = 0; u < UT; ++u)
#pragma unroll
                for (int e = 0; e < 4; ++e) xc[u][e] = xn[u][e];
        }
    }

    // ---- butterfly reduce over the 4 dl lanes ----
#pragma unroll
    for (int u = 0; u < UT; ++u)
#pragma unroll
        for (int kk = 0; kk < 13; ++kk) {
            float v = acc[u][kk];
            v += __shfl_xor(v, 1);
            v += __shfl_xor(v, 2);
            acc[u][kk] = v;
        }

    // ---- reshape via LDS into token-major [128][28] (static reg indices) ----
    __syncthreads();                      // done reading wlds
    float* red = wlds;
    if (dl == 0) {
#pragma unroll
        for (int u = 0; u < UT; ++u) {
            const int tloc = th * 16 + ts + 32 * u;
#pragma unroll
            for (int kk = 0; kk < KHN; ++kk)
                red[tloc * PPT + kh * KHN + kk] = acc[u][kk];
            if (kh == 0) red[tloc * PPT + 24] = acc[u][12];
        }
    }
    __syncthreads();

    // ---- block-copy 128*28 floats = 896 float4 (contiguous global write) ----
    float4* dst = (float4*)(part + ((size_t)grp * NTOK + (size_t)tile * TOKB) * PPT);
    const float4* srcv = (const float4*)red;
#pragma unroll
    for (int w = 0; w < 4; ++w) {
        const int i = t + w * TPB;
        if (i < (TOKB * PPT) / 4) dst[i] = srcv[i];
    }
}

// ---------------------------------------------------------------------------
// Kernel 3: finalize. Block = 32 tokens x 8 grp-octant lanes (256 blocks).
// ---------------------------------------------------------------------------
__global__ void finalize_k(const float* __restrict__ part,
                           const float* __restrict__ b_pre,
                           const float* __restrict__ b_post,
                           const float* __restrict__ b_res,
                           float* __restrict__ out) {
    const int t  = threadIdx.x;
    const int gq = t & 7;
    const int ts = t >> 3;
    const int tk = blockIdx.x * 32 + ts;

    float v[NACC];
#pragma unroll
    for (int c = 0; c < NACC; ++c) v[c] = 0.0f;
#pragma unroll
    for (int gg = 0; gg < 4; ++gg) {
        const int g = gq * 4 + gg;
        const float4* p4 = (const float4*)(part + ((size_t)g * NTOK + tk) * PPT);
        const float4 a0 = p4[0], a1 = p4[1], a2 = p4[2], a3 = p4[3];
        const float4 a4 = p4[4], a5 = p4[5], a6 = p4[6];
        v[0] += a0.x;  v[1] += a0.y;  v[2] += a0.z;  v[3] += a0.w;
        v[4] += a1.x;  v[5] += a1.y;  v[6] += a1.z;  v[7] += a1.w;
        v[8] += a2.x;  v[9] += a2.y;  v[10] += a2.z; v[11] += a2.w;
        v[12] += a3.x; v[13] += a3.y; v[14] += a3.z; v[15] += a3.w;
        v[16] += a4.x; v[17] += a4.y; v[18] += a4.z; v[19] += a4.w;
        v[20] += a5.x; v[21] += a5.y; v[22] += a5.z; v[23] += a5.w;
        v[24] += a6.x;                 // a6.yzw = pad, ignored
    }
#pragma unroll
    for (int c = 0; c < NACC; ++c) {
        float s = v[c];
        s += __shfl_xor(s, 1);
        s += __shfl_xor(s, 2);
        s += __shfl_xor(s, 4);
        v[c] = s;
    }

    const float rstd = rsqrtf(v[24] * (1.0f / (float)DM) + 1e-6f);

    float hp[4], hq[4];
#pragma unroll
    for (int j = 0; j < 4; ++j) {
        const float lp = fmaf(v[j], rstd, b_pre[j]);
        hp[j] = 1.0f / (1.0f + expf(-lp));
        const float lq = fmaf(v[4 + j], rstd, b_post[j]);
        hq[j] = 2.0f / (1.0f + expf(-lq));
    }

    // Sinkhorn-Knopp on 4x4, in registers; v_rcp_f32 for the 160 divides
    // (validated R7-R9: absmax identical 1.95e-3)
    float M[4][4];
#pragma unroll
    for (int i = 0; i < 4; ++i) {
        float l[4];
#pragma unroll
        for (int j = 0; j < 4; ++j)
            l[j] = fmaf(v[8 + i * 4 + j], rstd, b_res[i * 4 + j]);
        const float m = fmaxf(fmaxf(l[0], l[1]), fmaxf(l[2], l[3]));
#pragma unroll
        for (int j = 0; j < 4; ++j)
            M[i][j] = fmaxf(expf(l[j] - m), 1e-6f);
    }
    for (int it = 0; it < 20; ++it) {
#pragma unroll
        for (int i = 0; i < 4; ++i) {
            const float s = (M[i][0] + M[i][1]) + (M[i][2] + M[i][3]);
            const float inv = __builtin_amdgcn_rcpf(fmaxf(s, 1e-6f));
#pragma unroll
            for (int j = 0; j < 4; ++j) M[i][j] *= inv;
        }
#pragma unroll
        for (int j = 0; j < 4; ++j) {
            const float s = (M[0][j] + M[1][j]) + (M[2][j] + M[3][j]);
            const float inv = __builtin_amdgcn_rcpf(fmaxf(s, 1e-6f));
#pragma unroll
            for (int i = 0; i < 4; ++i) M[i][j] *= inv;
        }
    }

    float* out_pre  = out;                        // [NTOK][4]
    float* out_post = out + (size_t)NTOK * 4;     // [NTOK][4]
    float* out_res  = out + (size_t)NTOK * 8;     // [NTOK][16]
    if (gq == 0) {
        ((float4*)out_pre)[tk] = make_float4(hp[0], hp[1], hp[2], hp[3]);
    } else if (gq == 1) {
        ((float4*)out_post)[tk] = make_float4(hq[0], hq[1], hq[2], hq[3]);
    } else if (gq >= 4) {
        const int i = gq - 4;
        ((float4*)out_res)[tk * 4 + i] =
            make_float4(M[i][0], M[i][1], M[i][2], M[i][3]);
    }
}

// ---------------------------------------------------------------------------
extern "C" void kernel_launch(void* const* d_in, const int* in_sizes, int n_in,
                              void* d_out, int out_size, void* d_ws, size_t ws_size,
                              hipStream_t stream) {
    const float* x      = (const float*)d_in[0];   // (2,4096,4,2048) fp32
    const float* rms_w  = (const float*)d_in[1];   // (8192,)
    const float* w_pre  = (const float*)d_in[2];   // (4,8192)
    const float* w_post = (const float*)d_in[3];   // (4,8192)
    const float* w_res  = (const float*)d_in[4];   // (16,8192)
    const float* b_pre  = (const float*)d_in[5];   // (4,)
    const float* b_post = (const float*)d_in[6];   // (4,)
    const float* b_res  = (const float*)d_in[7];   // (4,4)
    const float* a_pre  = (const float*)d_in[8];   // scalar
    const float* a_post = (const float*)d_in[9];   // scalar
    const float* a_res  = (const float*)d_in[10];  // scalar
    float* out = (float*)d_out;

    // ws: Wc2 (196608 floats) + part (32*8192*28 = 7.34M floats) ~ 30.2 MB
    float* Wc2  = (float*)d_ws;
    float* part = (float*)d_ws + (size_t)NGRP * NK * DPG;

    combine_w<<<(NGRP * NK * DPG + TPB - 1) / TPB, TPB, 0, stream>>>(
        rms_w, w_pre, w_post, w_res, a_pre, a_post, a_res, Wc2);

    // grp fastest: co-resident blocks sweep contiguous token rows
    partial_k<<<dim3(NGRP, NTOK / TOKB), TPB, 0, stream>>>(x, Wc2, part);

    finalize_k<<<NTOK / 32, TPB, 0, stream>>>(part, b_pre, b_post, b_res, out);
}

// Round 11
// 57.014 us; speedup vs baseline: 1.5999x; 1.5999x over previous
//
#include <hip/hip_runtime.h>
#include <math.h>

// Problem constants (B=2, T=4096, n=4, D=2048)
#define DM      8192      // n*D flattened feature dim
#define NTOK    8192      // B*T tokens
#define NKS     256       // k-steps of 32 d over DM
#define TPB_C   256

typedef _Float16 f16x8 __attribute__((ext_vector_type(8)));
typedef float    f32x4 __attribute__((ext_vector_type(4)));

// ---------------------------------------------------------------------------
// Kernel 1: weight fragments, f16.
// Wh[kstep][frag][lane][i] = alpha_c * W_c[d] * rms_w[d], where
//   c = frag*16 + (lane&15)   (c>=24 -> 0 pad)
//   d = kstep*32 + (lane>>4)*8 + i
// This is exactly the B-operand lane layout of mfma_f32_16x16x32_f16
// (B[k][n]: lane l holds n = l%16, k = (l>>4)*8 + i), so the main kernel
// loads one b128 per fragment. 256*2*64*8 f16 = 512 KB, L2-resident.
// ---------------------------------------------------------------------------
__global__ void combine_w(const float* __restrict__ rms_w,
                          const float* __restrict__ w_pre,
                          const float* __restrict__ w_post,
                          const float* __restrict__ w_res,
                          const float* __restrict__ a_pre,
                          const float* __restrict__ a_post,
                          const float* __restrict__ a_res,
                          _Float16* __restrict__ Wh) {
    const int idx = blockIdx.x * blockDim.x + threadIdx.x;
    if (idx >= NKS * 2 * 64 * 8) return;
    const int i  = idx & 7;
    const int l  = (idx >> 3) & 63;
    const int f  = (idx >> 9) & 1;
    const int ks = idx >> 10;
    const int c  = f * 16 + (l & 15);
    const int d  = ks * 32 + (l >> 4) * 8 + i;
    float v = 0.0f;
    if (c < 24) {
        float w, a;
        if (c < 4)      { w = w_pre [(size_t)c       * DM + d]; a = a_pre[0];  }
        else if (c < 8) { w = w_post[(size_t)(c - 4) * DM + d]; a = a_post[0]; }
        else            { w = w_res [(size_t)(c - 8) * DM + d]; a = a_res[0];  }
        v = a * w * rms_w[d];
    }
    Wh[idx] = (_Float16)v;
}

// ---------------------------------------------------------------------------
// Kernel 2: FUSED dots + rms + sigmoid + Sinkhorn. Block = 16 tokens, 8 waves.
//  Wave wv owns d-range [wv*1024, (wv+1)*1024) = 32 k-steps of 32 d.
//  Per step: A-frag = x[tok0 + (l&15)][k0 + (l>>4)*8 ..+8) fp32 -> f16 (RNE),
//  B-frags from Wh (b128), 2x mfma_f32_16x16x32_f16 into f32x4 accs,
//  ss accumulated in fp32 on VALU (exact, as before).
//  D-frag: lane l reg r -> (tok=(l>>4)*4+r, coeff=l&15) [m89-verified layout].
//  Cross-wave reduce in LDS; Sinkhorn epilogue on wave 0 (16 tok x 4 gq).
//  No partial round-trip, no second pass: HBM = 268 MB x-read + 0.8 MB out.
// ---------------------------------------------------------------------------
__global__ __launch_bounds__(512) void fused_k(const float* __restrict__ x,
                                               const _Float16* __restrict__ Wh,
                                               const float* __restrict__ b_pre,
                                               const float* __restrict__ b_post,
                                               const float* __restrict__ b_res,
                                               float* __restrict__ out) {
    __shared__ float ldsA[2][8 * 256];   // [frag][wave*256 + lane*4 + reg]
    __shared__ float ldsS[8][16];        // [wave][tok] ss partials
    __shared__ float ldsF[16 * 28];      // [tok][28] final sums (24 dots + ss)

    const int t    = threadIdx.x;
    const int wv   = t >> 6;             // 0..7
    const int l    = t & 63;
    const int row  = l & 15;             // token row within tile
    const int kg   = l >> 4;             // k-group 0..3
    const int tok0 = blockIdx.x * 16;

    const float* xr = x + (size_t)(tok0 + row) * DM + wv * 1024 + kg * 8;
    const _Float16* wb = Wh + (size_t)wv * 32 * 1024;   // wv*32 ksteps * 1024

    f32x4 acc0 = {0.f, 0.f, 0.f, 0.f};
    f32x4 acc1 = {0.f, 0.f, 0.f, 0.f};
    float ss = 0.0f;

    for (int s = 0; s < 32; ++s) {
        const float4 xa = *(const float4*)(xr + s * 32);
        const float4 xb = *(const float4*)(xr + s * 32 + 4);
        const f16x8 b0 = *(const f16x8*)(wb + ((s * 2 + 0) * 64 + l) * 8);
        const f16x8 b1 = *(const f16x8*)(wb + ((s * 2 + 1) * 64 + l) * 8);
        f16x8 af;
        af[0] = (_Float16)xa.x; af[1] = (_Float16)xa.y;
        af[2] = (_Float16)xa.z; af[3] = (_Float16)xa.w;
        af[4] = (_Float16)xb.x; af[5] = (_Float16)xb.y;
        af[6] = (_Float16)xb.z; af[7] = (_Float16)xb.w;
        acc0 = __builtin_amdgcn_mfma_f32_16x16x32_f16(af, b0, acc0, 0, 0, 0);
        acc1 = __builtin_amdgcn_mfma_f32_16x16x32_f16(af, b1, acc1, 0, 0, 0);
        ss = fmaf(xa.x, xa.x, ss); ss = fmaf(xa.y, xa.y, ss);
        ss = fmaf(xa.z, xa.z, ss); ss = fmaf(xa.w, xa.w, ss);
        ss = fmaf(xb.x, xb.x, ss); ss = fmaf(xb.y, xb.y, ss);
        ss = fmaf(xb.z, xb.z, ss); ss = fmaf(xb.w, xb.w, ss);
    }

    // ss: fold the 4 k-groups (lanes row, row+16, row+32, row+48)
    ss += __shfl_xor(ss, 16);
    ss += __shfl_xor(ss, 32);
    if (l < 16) ldsS[wv][l] = ss;

    *(f32x4*)&ldsA[0][wv * 256 + l * 4] = acc0;
    *(f32x4*)&ldsA[1][wv * 256 + l * 4] = acc1;
    __syncthreads();

    // ---- cross-wave reduce: 384 dot jobs + 16 ss jobs -> ldsF ----
    if (t < 384) {
        const int tok = t / 24;
        const int c   = t - tok * 24;
        const int fi  = (c < 16) ? 0 : 1;
        const int src = ((tok >> 2) << 4) | (c & 15);   // D-frag lane
        const int reg = tok & 3;                         // D-frag reg
        float v = 0.0f;
#pragma unroll
        for (int w = 0; w < 8; ++w)
            v += ldsA[fi][w * 256 + src * 4 + reg];
        ldsF[tok * 28 + c] = v;
    } else if (t < 400) {
        const int tok = t - 384;
        float v = 0.0f;
#pragma unroll
        for (int w = 0; w < 8; ++w) v += ldsS[w][tok];
        ldsF[tok * 28 + 24] = v;
    }
    __syncthreads();

    // ---- epilogue: wave 0, 16 tok x 4 gq (duplicated math, split writes) ----
    if (t < 64) {
        const int tok = t >> 2;
        const int gq  = t & 3;
        const int tk  = tok0 + tok;

        float v[28];
#pragma unroll
        for (int q = 0; q < 7; ++q)
            *(float4*)&v[q * 4] = *(const float4*)&ldsF[tok * 28 + q * 4];

        const float rstd = rsqrtf(v[24] * (1.0f / (float)DM) + 1e-6f);

        float hp[4], hq[4];
#pragma unroll
        for (int j = 0; j < 4; ++j) {
            const float lp = fmaf(v[j], rstd, b_pre[j]);
            hp[j] = 1.0f / (1.0f + expf(-lp));
            const float lq = fmaf(v[4 + j], rstd, b_post[j]);
            hq[j] = 2.0f / (1.0f + expf(-lq));
        }

        // Sinkhorn-Knopp 4x4 in registers (rcpf validated R7-R10)
        float M[4][4];
#pragma unroll
        for (int i = 0; i < 4; ++i) {
            float lg[4];
#pragma unroll
            for (int j = 0; j < 4; ++j)
                lg[j] = fmaf(v[8 + i * 4 + j], rstd, b_res[i * 4 + j]);
            const float m = fmaxf(fmaxf(lg[0], lg[1]), fmaxf(lg[2], lg[3]));
#pragma unroll
            for (int j = 0; j < 4; ++j)
                M[i][j] = fmaxf(expf(lg[j] - m), 1e-6f);
        }
        for (int it = 0; it < 20; ++it) {
#pragma unroll
            for (int i = 0; i < 4; ++i) {
                const float s = (M[i][0] + M[i][1]) + (M[i][2] + M[i][3]);
                const float inv = __builtin_amdgcn_rcpf(fmaxf(s, 1e-6f));
#pragma unroll
                for (int j = 0; j < 4; ++j) M[i][j] *= inv;
            }
#pragma unroll
            for (int j = 0; j < 4; ++j) {
                const float s = (M[0][j] + M[1][j]) + (M[2][j] + M[3][j]);
                const float inv = __builtin_amdgcn_rcpf(fmaxf(s, 1e-6f));
#pragma unroll
                for (int i = 0; i < 4; ++i) M[i][j] *= inv;
            }
        }

        float* out_pre  = out;                        // [NTOK][4]
        float* out_post = out + (size_t)NTOK * 4;     // [NTOK][4]
        float* out_res  = out + (size_t)NTOK * 8;     // [NTOK][16]
        if (gq == 0) {
            ((float4*)out_pre)[tk] = make_float4(hp[0], hp[1], hp[2], hp[3]);
        } else if (gq == 1) {
            ((float4*)out_post)[tk] = make_float4(hq[0], hq[1], hq[2], hq[3]);
        } else if (gq == 2) {
            ((float4*)out_res)[tk * 4 + 0] = make_float4(M[0][0], M[0][1], M[0][2], M[0][3]);
            ((float4*)out_res)[tk * 4 + 1] = make_float4(M[1][0], M[1][1], M[1][2], M[1][3]);
        } else {
            ((float4*)out_res)[tk * 4 + 2] = make_float4(M[2][0], M[2][1], M[2][2], M[2][3]);
            ((float4*)out_res)[tk * 4 + 3] = make_float4(M[3][0], M[3][1], M[3][2], M[3][3]);
        }
    }
}

// ---------------------------------------------------------------------------
extern "C" void kernel_launch(void* const* d_in, const int* in_sizes, int n_in,
                              void* d_out, int out_size, void* d_ws, size_t ws_size,
                              hipStream_t stream) {
    const float* x      = (const float*)d_in[0];   // (2,4096,4,2048) fp32
    const float* rms_w  = (const float*)d_in[1];   // (8192,)
    const float* w_pre  = (const float*)d_in[2];   // (4,8192)
    const float* w_post = (const float*)d_in[3];   // (4,8192)
    const float* w_res  = (const float*)d_in[4];   // (16,8192)
    const float* b_pre  = (const float*)d_in[5];   // (4,)
    const float* b_post = (const float*)d_in[6];   // (4,)
    const float* b_res  = (const float*)d_in[7];   // (4,4)
    const float* a_pre  = (const float*)d_in[8];   // scalar
    const float* a_post = (const float*)d_in[9];   // scalar
    const float* a_res  = (const float*)d_in[10];  // scalar
    float* out = (float*)d_out;

    _Float16* Wh = (_Float16*)d_ws;                // 512 KB of ws

    combine_w<<<(NKS * 2 * 64 * 8 + TPB_C - 1) / TPB_C, TPB_C, 0, stream>>>(
        rms_w, w_pre, w_post, w_res, a_pre, a_post, a_res, Wh);

    fused_k<<<NTOK / 16, 512, 0, stream>>>(x, Wh, b_pre, b_post, b_res, out);
}